// Round 15
// baseline (199.485 us; speedup 1.0000x reference)
//
#include <hip/hip_runtime.h>
#include <math.h>

typedef float floatx4 __attribute__((ext_vector_type(4)));

#define NAG   32
#define NOBS  16
#define NN    80
#define KK    5
#define EKNN  400   // NN*KK
#define ED    416   // EKNN + NOBS
#define HID   128
#define TPB   1024

// swizzle for bf16 rows (32 uint2-chunks of 4 bf16 per row)
__device__ __forceinline__ int hswz(int n, int p) { return p ^ ((n & 3) << 3); }

__device__ __forceinline__ float bfhi_f(unsigned u) {
    union { unsigned u; float f; } v; v.u = u & 0xffff0000u; return v.f;
}
__device__ __forceinline__ float bflo_f(unsigned u) {
    union { unsigned u; float f; } v; v.u = u << 16; return v.f;
}
__device__ __forceinline__ unsigned f_bf_rne(float f) {   // 16-bit bf16 in low bits
    union { float f; unsigned u; } v; v.f = f;
    return (v.u + 0x7fffu + ((v.u >> 16) & 1u)) >> 16;
}
__device__ __forceinline__ uint2 pack_bf4v(floatx4 a) {
    uint2 r;
    r.x = f_bf_rne(a[0]) | (f_bf_rne(a[1]) << 16);
    r.y = f_bf_rne(a[2]) | (f_bf_rne(a[3]) << 16);
    return r;
}
__device__ __forceinline__ floatx4 unpack_bf4v(uint2 p) {
    floatx4 r;
    r[0] = bflo_f(p.x); r[1] = bfhi_f(p.x);
    r[2] = bflo_f(p.y); r[3] = bfhi_f(p.y);
    return r;
}

// ---- layer-1 node-linear (F_IN=5, tiny W read direct from global) ----
__device__ __forceinline__ void nl_pass5(const float* xf,
    const float* __restrict__ W, const float* __restrict__ bv,
    uint2* dstB, int t)
{
    const int q  = t & 31;
    const int ng = t >> 5;
    const int n0 = ng, n1 = ng + 32, n2 = 64 + (ng & 15);
    floatx4 a0 = {0.f,0.f,0.f,0.f}, a1 = a0, a2 = a0;
#pragma unroll
    for (int fi = 0; fi < 5; ++fi) {
        floatx4 wv = *(const floatx4*)(W + fi*HID + q*4);
        a0 += xf[n0*5 + fi] * wv;
        a1 += xf[n1*5 + fi] * wv;
        a2 += xf[n2*5 + fi] * wv;
    }
    floatx4 b4 = *(const floatx4*)(bv + q*4);
    a0 += b4; a1 += b4; a2 += b4;
    dstB[n0*32 + hswz(n0, q)] = pack_bf4v(a0);
    dstB[n1*32 + hswz(n1, q)] = pack_bf4v(a1);
    if (ng < 16) dstB[n2*32 + hswz(n2, q)] = pack_bf4v(a2);
}

// ---- layer-2 node-linear (F_IN=128) with W staged in LDS chunks ----
// W leaves L2 ONCE PER BLOCK (4 chunks x 16KB, coalesced float4 stage) instead
// of once per wave (r11/r12: 4-8GB of L2 W-streaming across the dispatch — the
// measured bottleneck). Thread: q = t&31 (f4 col), ng = t>>5; nodes ng, ng+32
// always, node 64+(ng&15) computed by ALL (no divergence) but written by ng<16.
// Alias safety (dstB == hxr_in on the Wr call): each h row n is read only by
// half-wave ng=n%32 / tail half-wave, which also writes xr[n] AFTER all its
// reads (post-loop, wave-lockstep). Internal barriers don't break this.
__device__ __forceinline__ void nl_pass128(const uint2* hxr_in,
    const float* __restrict__ W, const float* __restrict__ bv,
    float* wchunkS, uint2* dstB, int t)
{
    const int q  = t & 31;
    const int ng = t >> 5;
    const int n0 = ng, n1 = ng + 32, n2 = 64 + (ng & 15);
    const int ro0 = n0*32, rs0 = (n0 & 3) << 3;
    const int ro1 = n1*32, rs1 = (n1 & 3) << 3;
    const int ro2 = n2*32, rs2 = (n2 & 3) << 3;
    floatx4 a0 = {0.f,0.f,0.f,0.f}, a1 = a0, a2 = a0;

#pragma unroll 1
    for (int kc = 0; kc < 4; kc++) {          // 32 K-rows per chunk
        // stage chunk: 4096 floats, one float4 per thread, coalesced
        ((floatx4*)wchunkS)[t] = *(const floatx4*)(W + kc*4096 + t*4);
        __syncthreads();
#pragma unroll 1
        for (int f4l = 0; f4l < 8; f4l++) {
            const int f4 = kc*8 + f4l;
            uint2 p0 = hxr_in[ro0 + (f4 ^ rs0)];
            uint2 p1 = hxr_in[ro1 + (f4 ^ rs1)];
            uint2 p2 = hxr_in[ro2 + (f4 ^ rs2)];
#pragma unroll
            for (int u = 0; u < 4; u++) {
                floatx4 wv = *(const floatx4*)(wchunkS + (f4l*4 + u)*HID + q*4);
                unsigned w0 = (u < 2) ? p0.x : p0.y;
                unsigned w1 = (u < 2) ? p1.x : p1.y;
                unsigned w2 = (u < 2) ? p2.x : p2.y;
                float h0 = (u & 1) ? bfhi_f(w0) : bflo_f(w0);
                float h1 = (u & 1) ? bfhi_f(w1) : bflo_f(w1);
                float h2 = (u & 1) ? bfhi_f(w2) : bflo_f(w2);
                a0 += h0 * wv;
                a1 += h1 * wv;
                a2 += h2 * wv;
            }
        }
        __syncthreads();   // protect chunk before next stage overwrites
    }

    floatx4 b4 = *(const floatx4*)(bv + q*4);
    a0 += b4; a1 += b4; a2 += b4;
    dstB[n0*32 + hswz(n0, q)] = pack_bf4v(a0);
    dstB[n1*32 + hswz(n1, q)] = pack_bf4v(a1);
    if (ng < 16) dstB[n2*32 + hswz(n2, q)] = pack_bf4v(a2);
}

// ---- edge logits: lane owns f4 col q = t&31, group t>>5 owns 13 edges ----
__device__ __forceinline__ void edge_logits(const uint2* xlB, const uint2* xrB,
    const float* eaS, const int* nbr, const int* gmask,
    const float* weS, const float* attS, float* logitS, int t)
{
    const int q   = t & 31;
    const int grp = t >> 5;      // 0..31, edges grp*13 .. grp*13+12

#pragma unroll 1
    for (int i = 0; i < 13; i++) {
        int e = grp*13 + i;
        int src, dst; bool act = true;
        if (e < EKNN) { dst = e / KK; src = nbr[e]; }
        else { int j = e - EKNN; src = j; dst = j + NAG; act = (gmask[j] != 0); }
        floatx4 sv = unpack_bf4v(xlB[src*32 + hswz(src, q)])
                   + unpack_bf4v(xrB[dst*32 + hswz(dst, q)]);
#pragma unroll
        for (int j = 0; j < 5; j++) {
            float ej = eaS[e*5 + j];
            sv += ej * ((const floatx4*)weS)[j*32 + q];
        }
        floatx4 at = ((const floatx4*)attS)[q];
        float part = 0.f;
#pragma unroll
        for (int c = 0; c < 4; c++) {
            float s = fmaxf(sv[c], 0.2f*sv[c]);   // leaky_relu(s, 0.2)
            part += s * at[c];
        }
        part += __shfl_xor(part, 16);
        part += __shfl_xor(part, 8);
        part += __shfl_xor(part, 4);
        part += __shfl_xor(part, 2);
        part += __shfl_xor(part, 1);
        if (q == 0 && act) logitS[e] = part;
    }
}

// ---- per-dst softmax over incoming edges (5 knn + optional goal edge) ----
__device__ __forceinline__ void seg_softmax(const float* logitS, const int* gmask,
                                            float* alphaS, int t)
{
    if (t < NN) {
        const int n = t;
        float l[KK];
#pragma unroll
        for (int k = 0; k < KK; k++) l[k] = logitS[n*KK + k];
        float m = l[0];
#pragma unroll
        for (int k = 1; k < KK; k++) m = fmaxf(m, l[k]);
        int ge = -1; float lg = 0.f;
        if (n >= NAG && n < NAG + NOBS && gmask[n - NAG]) {
            ge = EKNN + (n - NAG);
            lg = logitS[ge];
            m = fmaxf(m, lg);
        }
        float s = 0.f, av[KK];
#pragma unroll
        for (int k = 0; k < KK; k++) { av[k] = expf(l[k] - m); s += av[k]; }
        float ag = 0.f;
        if (ge >= 0) { ag = expf(lg - m); s += ag; }
        float inv = 1.f / s;
#pragma unroll
        for (int k = 0; k < KK; k++) alphaS[n*KK + k] = av[k]*inv;
        if (ge >= 0) alphaS[ge] = ag*inv;
    }
}

// ---- h[n][f] = relu(bias[f] + sum_e alpha_e * xl[src_e][f]) -> bf16 hxrS ----
__device__ __forceinline__ void aggregate(const uint2* xlB, const float* alphaS,
                                          const int* nbr, const int* gmask,
                                          const float* __restrict__ bias,
                                          uint2* hxr, int t)
{
    for (int idx = t; idx < NN*32; idx += TPB) {
        int n = idx >> 5;
        int c = idx & 31;
        floatx4 acc = *(const floatx4*)(bias + 4*c);
#pragma unroll
        for (int k = 0; k < KK; k++) {
            float a = alphaS[n*KK + k];
            int s = nbr[n*KK + k];
            acc += a * unpack_bf4v(xlB[s*32 + hswz(s, c)]);
        }
        if (n >= NAG && n < NAG + NOBS && gmask[n - NAG]) {
            float a = alphaS[EKNN + (n - NAG)];
            int s = n - NAG;
            acc += a * unpack_bf4v(xlB[s*32 + hswz(s, c)]);
        }
#pragma unroll
        for (int c2 = 0; c2 < 4; c2++) acc[c2] = fmaxf(acc[c2], 0.f);
        hxr[n*32 + hswz(n, c)] = pack_bf4v(acc);
    }
}

// launch_bounds(1024, 8): VGPR budget 32 — the only config that co-schedules
// 2 blocks/CU (r7/r11/r12: 80-88% occupancy; vgpr 48/56/64 all -> 47%).
// LDS 77.6KB: 2x = 155KB <= 160KB.
__global__ __launch_bounds__(TPB, 8) void e3_kernel(
    const float* __restrict__ obst, const float* __restrict__ apos,
    const float* __restrict__ gpos, const float* __restrict__ avel,
    const float* __restrict__ Wl1, const float* __restrict__ bl1,
    const float* __restrict__ Wr1, const float* __restrict__ br1,
    const float* __restrict__ We1, const float* __restrict__ att1, const float* __restrict__ bias1,
    const float* __restrict__ Wl2, const float* __restrict__ bl2,
    const float* __restrict__ Wr2, const float* __restrict__ br2,
    const float* __restrict__ We2, const float* __restrict__ att2, const float* __restrict__ bias2,
    const float* __restrict__ Wl3, const float* __restrict__ bl3,
    const float* __restrict__ Wr3, const float* __restrict__ br3,
    const float* __restrict__ We3, const float* __restrict__ att3, const float* __restrict__ bias3,
    float* __restrict__ out)
{
    __shared__ float pos0[NN], pos1[NN], vel0[NN], vel1[NN], rad[NN];
    __shared__ float xfeat[NN*5];
    __shared__ int   nbr[NN*KK];
    __shared__ int   gmask[NOBS];
    __shared__ float eaS[ED*5];
    __shared__ float logitS[ED];
    __shared__ float alphaS[ED];
    __shared__ uint2 hxrS[NN*32];            // bf16 h AND bf16 xr (time-shared)
    __shared__ uint2 xlB[NN*32];             // bf16 xl
    __shared__ __align__(16) float wchunkS[32*HID];   // 16KB W chunk (32 K-rows)
    __shared__ float weS[5*HID];
    __shared__ float attS[HID];
    __shared__ float xl3S[NN], xr3S[NN];
    __shared__ float resS;

    const int g = blockIdx.x;
    const int t = threadIdx.x;

    // ---------- phase A: load graph ----------
    if (t < NN) {
        int n = t;
        float px, py, vx = 0.f, vy = 0.f, r;
        if (n < NAG) {
            px = apos[(g*NAG + n)*2 + 0]; py = apos[(g*NAG + n)*2 + 1];
            vx = avel[(g*NAG + n)*2 + 0]; vy = avel[(g*NAG + n)*2 + 1];
            r = 0.05f;
        } else if (n < 2*NAG) {
            int m = n - NAG;
            px = gpos[(g*NAG + m)*2 + 0]; py = gpos[(g*NAG + m)*2 + 1];
            r = 0.f;
        } else {
            int m = n - 2*NAG;
            px = obst[(g*NOBS + m)*2 + 0]; py = obst[(g*NOBS + m)*2 + 1];
            r = 0.1f;
        }
        pos0[n] = px; pos1[n] = py; vel0[n] = vx; vel1[n] = vy; rad[n] = r;
        xfeat[n*5 + 0] = (n < NAG) ? 1.f : 0.f;
        xfeat[n*5 + 1] = (n >= NAG && n < 2*NAG) ? 1.f : 0.f;
        xfeat[n*5 + 2] = (n >= 2*NAG) ? 1.f : 0.f;
        xfeat[n*5 + 3] = (n < NAG) ? sqrtf(__fadd_rn(__fmul_rn(vx,vx), __fmul_rn(vy,vy))) : 0.f;
        xfeat[n*5 + 4] = r;
    }
    __syncthreads();

    // ---------- phase B: kNN top-5 (ascending d2, stable on ties == top_k) ----------
    if (t < NN) {
        const int i = t;
        float bd[KK]; int bi[KK];
#pragma unroll
        for (int k = 0; k < KK; k++) { bd[k] = 3.4e38f; bi[k] = -1; }
        const float pix = pos0[i], piy = pos1[i];
        for (int j = 0; j < NN; j++) {
            float dx = __fsub_rn(pix, pos0[j]);
            float dy = __fsub_rn(piy, pos1[j]);
            float d2 = __fadd_rn(__fmul_rn(dx,dx), __fmul_rn(dy,dy));
            if (d2 < bd[KK-1]) {
                int p = KK - 1;
                while (p > 0 && d2 < bd[p-1]) { bd[p] = bd[p-1]; bi[p] = bi[p-1]; p--; }
                bd[p] = d2; bi[p] = j;
            }
        }
#pragma unroll
        for (int k = 0; k < KK; k++) nbr[i*KK + k] = bi[k];
    }
    __syncthreads();

    // goal-edge dedup mask
    if (t < NOBS) {
        int j = t, dup = 0;
#pragma unroll
        for (int k = 0; k < KK; k++) dup |= (nbr[(NAG + j)*KK + k] == j);
        gmask[j] = !dup;
    }
    __syncthreads();

    // ---------- phase C: edge attributes ----------
    for (int e = t; e < ED; e += TPB) {
        int src, dst;
        if (e < EKNN) { dst = e / KK; src = nbr[e]; }
        else          { src = e - EKNN; dst = src + NAG; }
        float pdx = pos0[src] - pos0[dst];
        float pdy = pos1[src] - pos1[dst];
        float dist = sqrtf(pdx*pdx + pdy*pdy);
        float inv = 1.f / fmaxf(dist, 1e-6f);
        float pnx = pdx * inv, pny = pdy * inv;
        float rvx = vel0[src] - vel0[dst];
        float rvy = vel1[src] - vel1[dst];
        eaS[e*5 + 0] = (src < NAG && dst == src + NAG) ? 1.f : 0.f;
        eaS[e*5 + 1] = dist;
        eaS[e*5 + 2] = dist - (rad[src] + rad[dst]);
        eaS[e*5 + 3] = rvx*pnx + rvy*pny;
        eaS[e*5 + 4] = rvx*pny - rvy*pnx;
    }
    __syncthreads();

    // ================= layers 1 & 2 (F_out = 128) =================
    const float* WlA[2]   = { Wl1, Wl2 };
    const float* blA[2]   = { bl1, bl2 };
    const float* WrA[2]   = { Wr1, Wr2 };
    const float* brA[2]   = { br1, br2 };
    const float* WeA[2]   = { We1, We2 };
    const float* attA[2]  = { att1, att2 };
    const float* biasA[2] = { bias1, bias2 };

    for (int L = 0; L < 2; L++) {
        // stage We/att into LDS (visibility via the GEMM-internal/после barriers)
        for (int i = t; i < 5*HID; i += TPB) weS[i] = WeA[L][i];
        for (int i = t; i < HID;  i += TPB) attS[i] = attA[L][i];

        if (L == 0) {
            nl_pass5(xfeat, WlA[0], blA[0], xlB,  t);
            nl_pass5(xfeat, WrA[0], brA[0], hxrS, t);
        } else {
            nl_pass128(hxrS, WlA[1], blA[1], wchunkS, xlB,  t);
            nl_pass128(hxrS, WrA[1], brA[1], wchunkS, hxrS, t);   // h->xr alias, safe
        }
        __syncthreads();

        edge_logits(xlB, hxrS, eaS, nbr, gmask, weS, attS, logitS, t);
        __syncthreads();

        seg_softmax(logitS, gmask, alphaS, t);
        __syncthreads();

        aggregate(xlB, alphaS, nbr, gmask, biasA[L], hxrS, t);
        __syncthreads();
    }

    // ================= layer 3 (F_out = 1) =================
    // node transform: lane owns col q, group grp handles nodes grp, grp+32, grp+64
    {
        const int q   = t & 31;
        const int grp = t >> 5;
        floatx4 wl4 = *(const floatx4*)(Wl3 + q*4);
        floatx4 wr4 = *(const floatx4*)(Wr3 + q*4);
#pragma unroll
        for (int rep = 0; rep < 3; rep++) {
            int n = grp + rep*32;
            if (n < NN) {
                floatx4 hv = unpack_bf4v(hxrS[n*32 + hswz(n, q)]);
                float al = hv[0]*wl4[0] + hv[1]*wl4[1] + hv[2]*wl4[2] + hv[3]*wl4[3];
                float ar = hv[0]*wr4[0] + hv[1]*wr4[1] + hv[2]*wr4[2] + hv[3]*wr4[3];
                al += __shfl_xor(al, 16); ar += __shfl_xor(ar, 16);
                al += __shfl_xor(al, 8);  ar += __shfl_xor(ar, 8);
                al += __shfl_xor(al, 4);  ar += __shfl_xor(ar, 4);
                al += __shfl_xor(al, 2);  ar += __shfl_xor(ar, 2);
                al += __shfl_xor(al, 1);  ar += __shfl_xor(ar, 1);
                if (q == 0) {
                    xl3S[n] = al + bl3[0];
                    xr3S[n] = ar + br3[0];
                }
            }
        }
    }
    __syncthreads();

    {
        float w0 = We3[0], w1 = We3[1], w2 = We3[2], w3 = We3[3], w4 = We3[4];
        float a0 = att3[0];
        for (int e = t; e < ED; e += TPB) {
            int src, dst;
            if (e < EKNN) { dst = e / KK; src = nbr[e]; }
            else { src = e - EKNN; dst = src + NAG; if (!gmask[src]) continue; }
            float s = xl3S[src] + xr3S[dst]
                    + eaS[e*5+0]*w0 + eaS[e*5+1]*w1 + eaS[e*5+2]*w2
                    + eaS[e*5+3]*w3 + eaS[e*5+4]*w4;
            s = fmaxf(s, 0.2f*s);
            logitS[e] = s * a0;
        }
    }
    __syncthreads();

    seg_softmax(logitS, gmask, alphaS, t);
    __syncthreads();

    // final: sum over agent nodes of (bias3 + sum_e alpha*xl3[src]); broadcast to 32 outputs
    float v = 0.f;
    if (t < NAG) {
        v = bias3[0];
#pragma unroll
        for (int k = 0; k < KK; k++) v += alphaS[t*KK + k] * xl3S[nbr[t*KK + k]];
    }
    if (t < 64) {
#pragma unroll
        for (int o = 32; o > 0; o >>= 1) v += __shfl_xor(v, o);
        if (t == 0) resS = v;
    }
    __syncthreads();
    if (t < NAG) out[g*NAG + t] = resS;
}

extern "C" void kernel_launch(void* const* d_in, const int* in_sizes, int n_in,
                              void* d_out, int out_size, void* d_ws, size_t ws_size,
                              hipStream_t stream)
{
    const float* obst = (const float*)d_in[0];
    const float* apos = (const float*)d_in[1];
    const float* gpos = (const float*)d_in[2];
    const float* avel = (const float*)d_in[3];
    const int B = in_sizes[1] / (NAG * 2);

    e3_kernel<<<B, TPB, 0, stream>>>(
        obst, apos, gpos, avel,
        (const float*)d_in[4],  (const float*)d_in[5],  (const float*)d_in[6],
        (const float*)d_in[7],  (const float*)d_in[8],  (const float*)d_in[9],
        (const float*)d_in[10],
        (const float*)d_in[11], (const float*)d_in[12], (const float*)d_in[13],
        (const float*)d_in[14], (const float*)d_in[15], (const float*)d_in[16],
        (const float*)d_in[17],
        (const float*)d_in[18], (const float*)d_in[19], (const float*)d_in[20],
        (const float*)d_in[21], (const float*)d_in[22], (const float*)d_in[23],
        (const float*)d_in[24],
        (float*)d_out);
}

// Round 16
// 129.339 us; speedup vs baseline: 1.5423x; 1.5423x over previous
//
#include <hip/hip_runtime.h>
#include <math.h>

typedef float floatx4 __attribute__((ext_vector_type(4)));
typedef short bf16x8  __attribute__((ext_vector_type(8)));   // 8 bf16 = 4 VGPRs (guide §3)

#define NAG   32
#define NOBS  16
#define NN    80
#define KK    5
#define EKNN  400   // NN*KK
#define ED    416   // EKNN + NOBS
#define HID   128
#define TPB   1024

// bf16-row swizzle, uint2-chunk units. (n&7)<<1 puts row bits into LDS banks so
// MFMA A-fragment reads (16 rows/quarter-wave at fixed chunk) are 2-way-free;
// per-lane-column readers (edge/aggregate/L3) are conflict-free under any row-XOR.
__device__ __forceinline__ int bsw(int n, int c) { return c ^ ((n & 7) << 1); }

__device__ __forceinline__ float bfhi_f(unsigned u) {
    union { unsigned u; float f; } v; v.u = u & 0xffff0000u; return v.f;
}
__device__ __forceinline__ float bflo_f(unsigned u) {
    union { unsigned u; float f; } v; v.u = u << 16; return v.f;
}
__device__ __forceinline__ unsigned f_bf_rne(float f) {   // bf16 in low 16 bits
    union { float f; unsigned u; } v; v.f = f;
    return (v.u + 0x7fffu + ((v.u >> 16) & 1u)) >> 16;
}
__device__ __forceinline__ uint2 pack_bf4v(floatx4 a) {
    uint2 r;
    r.x = f_bf_rne(a[0]) | (f_bf_rne(a[1]) << 16);
    r.y = f_bf_rne(a[2]) | (f_bf_rne(a[3]) << 16);
    return r;
}
__device__ __forceinline__ floatx4 unpack_bf4v(uint2 p) {
    floatx4 r;
    r[0] = bflo_f(p.x); r[1] = bfhi_f(p.x);
    r[2] = bflo_f(p.y); r[3] = bfhi_f(p.y);
    return r;
}

// ---- layer-1 node-linear (F_IN=5, tiny W read direct from global) ----
__device__ __forceinline__ void nl_pass5(const float* xf,
    const float* __restrict__ W, const float* __restrict__ bv,
    uint2* dstB, int t)
{
    const int q  = t & 31;
    const int ng = t >> 5;
    const int n0 = ng, n1 = ng + 32, n2 = 64 + (ng & 15);
    floatx4 a0 = {0.f,0.f,0.f,0.f}, a1 = a0, a2 = a0;
#pragma unroll
    for (int fi = 0; fi < 5; ++fi) {
        floatx4 wv = *(const floatx4*)(W + fi*HID + q*4);
        a0 += xf[n0*5 + fi] * wv;
        a1 += xf[n1*5 + fi] * wv;
        a2 += xf[n2*5 + fi] * wv;
    }
    floatx4 b4 = *(const floatx4*)(bv + q*4);
    a0 += b4; a1 += b4; a2 += b4;
    dstB[n0*32 + bsw(n0, q)] = pack_bf4v(a0);
    dstB[n1*32 + bsw(n1, q)] = pack_bf4v(a1);
    if (ng < 16) dstB[n2*32 + bsw(n2, q)] = pack_bf4v(a2);
}

// ---- MFMA D-tile store: D(row,col) = acc[rr] + bias[col] -> bf16 @ bsw layout ----
__device__ __forceinline__ void store_tile(floatx4 ac, int mtbase, int l, int col,
                                           float bval, char* dbase)
{
#pragma unroll
    for (int rr = 0; rr < 4; rr++) {
        int row = mtbase + ((l >> 4) << 2) + rr;
        int ch  = (col >> 2) ^ ((row & 7) << 1);
        *(unsigned short*)(dbase + row*256 + ch*8 + (col & 3)*2) =
            (unsigned short)f_bf_rne(ac[rr] + bval);
    }
}

// ---- edge logits: lane owns f4 col q = t&31, group t>>5 owns 13 edges ----
__device__ __forceinline__ void edge_logits(const uint2* xlB, const uint2* xrB,
    const float* eaS, const int* nbr, const int* gmask,
    const float* weS, const float* attS, float* logitS, int t)
{
    const int q   = t & 31;
    const int grp = t >> 5;      // 0..31, edges grp*13 .. grp*13+12

#pragma unroll 1
    for (int i = 0; i < 13; i++) {
        int e = grp*13 + i;
        int src, dst; bool act = true;
        if (e < EKNN) { dst = e / KK; src = nbr[e]; }
        else { int j = e - EKNN; src = j; dst = j + NAG; act = (gmask[j] != 0); }
        floatx4 sv = unpack_bf4v(xlB[src*32 + bsw(src, q)])
                   + unpack_bf4v(xrB[dst*32 + bsw(dst, q)]);
#pragma unroll
        for (int j = 0; j < 5; j++) {
            float ej = eaS[e*5 + j];
            sv += ej * ((const floatx4*)weS)[j*32 + q];
        }
        floatx4 at = ((const floatx4*)attS)[q];
        float part = 0.f;
#pragma unroll
        for (int c = 0; c < 4; c++) {
            float s = fmaxf(sv[c], 0.2f*sv[c]);   // leaky_relu(s, 0.2)
            part += s * at[c];
        }
        part += __shfl_xor(part, 16);
        part += __shfl_xor(part, 8);
        part += __shfl_xor(part, 4);
        part += __shfl_xor(part, 2);
        part += __shfl_xor(part, 1);
        if (q == 0 && act) logitS[e] = part;
    }
}

// ---- per-dst softmax over incoming edges (5 knn + optional goal edge) ----
__device__ __forceinline__ void seg_softmax(const float* logitS, const int* gmask,
                                            float* alphaS, int t)
{
    if (t < NN) {
        const int n = t;
        float l[KK];
#pragma unroll
        for (int k = 0; k < KK; k++) l[k] = logitS[n*KK + k];
        float m = l[0];
#pragma unroll
        for (int k = 1; k < KK; k++) m = fmaxf(m, l[k]);
        int ge = -1; float lg = 0.f;
        if (n >= NAG && n < NAG + NOBS && gmask[n - NAG]) {
            ge = EKNN + (n - NAG);
            lg = logitS[ge];
            m = fmaxf(m, lg);
        }
        float s = 0.f, av[KK];
#pragma unroll
        for (int k = 0; k < KK; k++) { av[k] = expf(l[k] - m); s += av[k]; }
        float ag = 0.f;
        if (ge >= 0) { ag = expf(lg - m); s += ag; }
        float inv = 1.f / s;
#pragma unroll
        for (int k = 0; k < KK; k++) alphaS[n*KK + k] = av[k]*inv;
        if (ge >= 0) alphaS[ge] = ag*inv;
    }
}

// ---- h[n][f] = relu(bias[f] + sum_e alpha_e * xl[src_e][f]) -> bf16 hxrS ----
__device__ __forceinline__ void aggregate(const uint2* xlB, const float* alphaS,
                                          const int* nbr, const int* gmask,
                                          const float* __restrict__ bias,
                                          uint2* hxr, int t)
{
    for (int idx = t; idx < NN*32; idx += TPB) {
        int n = idx >> 5;
        int c = idx & 31;
        floatx4 acc = *(const floatx4*)(bias + 4*c);
#pragma unroll
        for (int k = 0; k < KK; k++) {
            float a = alphaS[n*KK + k];
            int s = nbr[n*KK + k];
            acc += a * unpack_bf4v(xlB[s*32 + bsw(s, c)]);
        }
        if (n >= NAG && n < NAG + NOBS && gmask[n - NAG]) {
            float a = alphaS[EKNN + (n - NAG)];
            int s = n - NAG;
            acc += a * unpack_bf4v(xlB[s*32 + bsw(s, c)]);
        }
#pragma unroll
        for (int c2 = 0; c2 < 4; c2++) acc[c2] = fmaxf(acc[c2], 0.f);
        hxr[n*32 + bsw(n, c)] = pack_bf4v(acc);
    }
}

// launch_bounds(1024, 8): VGPR budget 32 — the only config that co-schedules
// 2 blocks/CU (empirical: vgpr=32 -> 80-89% occupancy; 48/56/64 -> 47%).
// LDS ~75.8KB: 2x <= 160KB.
__global__ __launch_bounds__(TPB, 8) void e3_kernel(
    const float* __restrict__ obst, const float* __restrict__ apos,
    const float* __restrict__ gpos, const float* __restrict__ avel,
    const float* __restrict__ Wl1, const float* __restrict__ bl1,
    const float* __restrict__ Wr1, const float* __restrict__ br1,
    const float* __restrict__ We1, const float* __restrict__ att1, const float* __restrict__ bias1,
    const float* __restrict__ Wl2, const float* __restrict__ bl2,
    const float* __restrict__ Wr2, const float* __restrict__ br2,
    const float* __restrict__ We2, const float* __restrict__ att2, const float* __restrict__ bias2,
    const float* __restrict__ Wl3, const float* __restrict__ bl3,
    const float* __restrict__ Wr3, const float* __restrict__ br3,
    const float* __restrict__ We3, const float* __restrict__ att3, const float* __restrict__ bias3,
    float* __restrict__ out)
{
    __shared__ float pos0[NN], pos1[NN], vel0[NN], vel1[NN], rad[NN];
    __shared__ float xfeat[NN*5];
    __shared__ int   nbr[NN*KK];
    __shared__ int   gmask[NOBS];
    __shared__ float eaS[ED*5];
    __shared__ float logitS[ED];
    __shared__ float alphaS[ED];
    __shared__ uint2 hxrS[NN*32];            // bf16 h AND bf16 xr (time-shared)
    __shared__ uint2 xlB[NN*32];             // bf16 xl
    __shared__ uint4 BfS[2*8*64];            // 16KB: B-fragments (Wl2+Wr2 32-k chunk)
    __shared__ float weS[5*HID];
    __shared__ float attS[HID];
    __shared__ float xl3S[NN], xr3S[NN];
    __shared__ float resS;

    const int g = blockIdx.x;
    const int t = threadIdx.x;

    // ---------- phase A: load graph ----------
    if (t < NN) {
        int n = t;
        float px, py, vx = 0.f, vy = 0.f, r;
        if (n < NAG) {
            px = apos[(g*NAG + n)*2 + 0]; py = apos[(g*NAG + n)*2 + 1];
            vx = avel[(g*NAG + n)*2 + 0]; vy = avel[(g*NAG + n)*2 + 1];
            r = 0.05f;
        } else if (n < 2*NAG) {
            int m = n - NAG;
            px = gpos[(g*NAG + m)*2 + 0]; py = gpos[(g*NAG + m)*2 + 1];
            r = 0.f;
        } else {
            int m = n - 2*NAG;
            px = obst[(g*NOBS + m)*2 + 0]; py = obst[(g*NOBS + m)*2 + 1];
            r = 0.1f;
        }
        pos0[n] = px; pos1[n] = py; vel0[n] = vx; vel1[n] = vy; rad[n] = r;
        xfeat[n*5 + 0] = (n < NAG) ? 1.f : 0.f;
        xfeat[n*5 + 1] = (n >= NAG && n < 2*NAG) ? 1.f : 0.f;
        xfeat[n*5 + 2] = (n >= 2*NAG) ? 1.f : 0.f;
        xfeat[n*5 + 3] = (n < NAG) ? sqrtf(__fadd_rn(__fmul_rn(vx,vx), __fmul_rn(vy,vy))) : 0.f;
        xfeat[n*5 + 4] = r;
    }
    __syncthreads();

    // ---------- phase B: kNN top-5 (ascending d2, stable on ties == top_k) ----------
    if (t < NN) {
        const int i = t;
        float bd[KK]; int bi[KK];
#pragma unroll
        for (int k = 0; k < KK; k++) { bd[k] = 3.4e38f; bi[k] = -1; }
        const float pix = pos0[i], piy = pos1[i];
        for (int j = 0; j < NN; j++) {
            float dx = __fsub_rn(pix, pos0[j]);
            float dy = __fsub_rn(piy, pos1[j]);
            float d2 = __fadd_rn(__fmul_rn(dx,dx), __fmul_rn(dy,dy));
            if (d2 < bd[KK-1]) {
                int p = KK - 1;
                while (p > 0 && d2 < bd[p-1]) { bd[p] = bd[p-1]; bi[p] = bi[p-1]; p--; }
                bd[p] = d2; bi[p] = j;
            }
        }
#pragma unroll
        for (int k = 0; k < KK; k++) nbr[i*KK + k] = bi[k];
    }
    __syncthreads();

    // goal-edge dedup mask
    if (t < NOBS) {
        int j = t, dup = 0;
#pragma unroll
        for (int k = 0; k < KK; k++) dup |= (nbr[(NAG + j)*KK + k] == j);
        gmask[j] = !dup;
    }
    __syncthreads();

    // ---------- phase C: edge attributes ----------
    for (int e = t; e < ED; e += TPB) {
        int src, dst;
        if (e < EKNN) { dst = e / KK; src = nbr[e]; }
        else          { src = e - EKNN; dst = src + NAG; }
        float pdx = pos0[src] - pos0[dst];
        float pdy = pos1[src] - pos1[dst];
        float dist = sqrtf(pdx*pdx + pdy*pdy);
        float inv = 1.f / fmaxf(dist, 1e-6f);
        float pnx = pdx * inv, pny = pdy * inv;
        float rvx = vel0[src] - vel0[dst];
        float rvy = vel1[src] - vel1[dst];
        eaS[e*5 + 0] = (src < NAG && dst == src + NAG) ? 1.f : 0.f;
        eaS[e*5 + 1] = dist;
        eaS[e*5 + 2] = dist - (rad[src] + rad[dst]);
        eaS[e*5 + 3] = rvx*pnx + rvy*pny;
        eaS[e*5 + 4] = rvx*pny - rvy*pnx;
    }
    __syncthreads();

    // ================= layer 1 (VALU, F_IN=5) =================
    for (int i = t; i < 5*HID; i += TPB) weS[i] = We1[i];
    for (int i = t; i < HID;  i += TPB) attS[i] = att1[i];
    nl_pass5(xfeat, Wl1, bl1, xlB,  t);
    nl_pass5(xfeat, Wr1, br1, hxrS, t);
    __syncthreads();
    edge_logits(xlB, hxrS, eaS, nbr, gmask, weS, attS, logitS, t);
    __syncthreads();
    seg_softmax(logitS, gmask, alphaS, t);
    __syncthreads();
    aggregate(xlB, alphaS, nbr, gmask, bias1, hxrS, t);
    __syncthreads();

    // ================= layer 2: dual GEMM on the MATRIX pipe =================
    // mfma_f32_16x16x32_bf16. Wave w: matrix = w>>3 (Wl2->xlB, Wr2->hxrS),
    // col-tile nt = w&7; 5 m-tiles (M=80) accumulated across K=128 (4 kb chunks).
    // Per chunk: all 1024 threads stage 32 k-rows of BOTH matrices as bf16
    // B-fragments (k-major coalesced global reads -> one ds_write_b128 each).
    // A-frags read from hxrS (h bf16, bsw layout): lane l -> row mt*16+(l&15),
    // k = kb*32 + 8*(l>>4) + j  == one b128 at chunk (kb*8+2*(l>>4))^bsw-xor.
    // xr2 overwrites h in hxrS only AFTER the final in-loop barrier (all
    // A-reads complete) -> no race.
    for (int i = t; i < 5*HID; i += TPB) weS[i] = We2[i];
    for (int i = t; i < HID;  i += TPB) attS[i] = att2[i];
    {
        const int w   = t >> 6;          // wave 0..15
        const int l   = t & 63;
        const int mat = w >> 3;
        const int nt  = w & 7;
        const int ar  = l & 15;
        const int kg2 = (l >> 4) << 1;
        const int arx = (ar & 7) << 1;

        const int sm = t >> 9;           // staging: matrix
        const int s  = t & 511;
        const int sn = s & 127;          // column
        const int g8 = s >> 7;           // k-octet 0..3
        const float* __restrict__ Wst = sm ? Wr2 : Wl2;
        const int swidx = sm*512 + (sn >> 4)*64 + ((sn & 15) | (g8 << 4));

        floatx4 acc0 = {0.f,0.f,0.f,0.f}, acc1 = acc0, acc2 = acc0,
                acc3 = acc0, acc4 = acc0;

#pragma unroll 1
        for (int kb = 0; kb < 4; ++kb) {
            // stage chunk kb (both matrices) as B-fragments
            const float* wp = Wst + (kb*32 + g8*8)*HID + sn;
            uint4 pk;
            pk.x = f_bf_rne(wp[0])     | (f_bf_rne(wp[HID])   << 16);
            pk.y = f_bf_rne(wp[2*HID]) | (f_bf_rne(wp[3*HID]) << 16);
            pk.z = f_bf_rne(wp[4*HID]) | (f_bf_rne(wp[5*HID]) << 16);
            pk.w = f_bf_rne(wp[6*HID]) | (f_bf_rne(wp[7*HID]) << 16);
            BfS[swidx] = pk;
            __syncthreads();

            bf16x8 bfrag = ((const bf16x8*)BfS)[mat*512 + nt*64 + l];
            const char* hbase = (const char*)hxrS;
            const int cA = ((kb*8 + kg2) ^ arx) * 8;
#define MT_MFMA(AC, MT) { \
            bf16x8 af = *(const bf16x8*)(hbase + (MT*4096) + ar*256 + cA); \
            AC = __builtin_amdgcn_mfma_f32_16x16x32_bf16(af, bfrag, AC, 0, 0, 0); }
            MT_MFMA(acc0, 0)
            MT_MFMA(acc1, 1)
            MT_MFMA(acc2, 2)
            MT_MFMA(acc3, 3)
            MT_MFMA(acc4, 4)
#undef MT_MFMA
            __syncthreads();   // chunk reuse fence; final iter = all h reads done
        }

        // write D = acc + bias (bf16, bsw layout)
        const float* __restrict__ bv = mat ? br2 : bl2;
        char* dbase = (char*)(mat ? hxrS : xlB);
        const int col = nt*16 + ar;
        const float bval = bv[col];
        store_tile(acc0,  0, l, col, bval, dbase);
        store_tile(acc1, 16, l, col, bval, dbase);
        store_tile(acc2, 32, l, col, bval, dbase);
        store_tile(acc3, 48, l, col, bval, dbase);
        store_tile(acc4, 64, l, col, bval, dbase);
    }
    __syncthreads();

    edge_logits(xlB, hxrS, eaS, nbr, gmask, weS, attS, logitS, t);
    __syncthreads();
    seg_softmax(logitS, gmask, alphaS, t);
    __syncthreads();
    aggregate(xlB, alphaS, nbr, gmask, bias2, hxrS, t);
    __syncthreads();

    // ================= layer 3 (F_out = 1) =================
    {
        const int q   = t & 31;
        const int grp = t >> 5;
        floatx4 wl4 = *(const floatx4*)(Wl3 + q*4);
        floatx4 wr4 = *(const floatx4*)(Wr3 + q*4);
#pragma unroll
        for (int rep = 0; rep < 3; rep++) {
            int n = grp + rep*32;
            if (n < NN) {
                floatx4 hv = unpack_bf4v(hxrS[n*32 + bsw(n, q)]);
                float al = hv[0]*wl4[0] + hv[1]*wl4[1] + hv[2]*wl4[2] + hv[3]*wl4[3];
                float ar3 = hv[0]*wr4[0] + hv[1]*wr4[1] + hv[2]*wr4[2] + hv[3]*wr4[3];
                al += __shfl_xor(al, 16); ar3 += __shfl_xor(ar3, 16);
                al += __shfl_xor(al, 8);  ar3 += __shfl_xor(ar3, 8);
                al += __shfl_xor(al, 4);  ar3 += __shfl_xor(ar3, 4);
                al += __shfl_xor(al, 2);  ar3 += __shfl_xor(ar3, 2);
                al += __shfl_xor(al, 1);  ar3 += __shfl_xor(ar3, 1);
                if (q == 0) {
                    xl3S[n] = al + bl3[0];
                    xr3S[n] = ar3 + br3[0];
                }
            }
        }
    }
    __syncthreads();

    {
        float w0 = We3[0], w1 = We3[1], w2 = We3[2], w3 = We3[3], w4 = We3[4];
        float a0 = att3[0];
        for (int e = t; e < ED; e += TPB) {
            int src, dst;
            if (e < EKNN) { dst = e / KK; src = nbr[e]; }
            else { src = e - EKNN; dst = src + NAG; if (!gmask[src]) continue; }
            float s = xl3S[src] + xr3S[dst]
                    + eaS[e*5+0]*w0 + eaS[e*5+1]*w1 + eaS[e*5+2]*w2
                    + eaS[e*5+3]*w3 + eaS[e*5+4]*w4;
            s = fmaxf(s, 0.2f*s);
            logitS[e] = s * a0;
        }
    }
    __syncthreads();

    seg_softmax(logitS, gmask, alphaS, t);
    __syncthreads();

    // final: sum over agent nodes of (bias3 + sum_e alpha*xl3[src]); broadcast to 32 outputs
    float v = 0.f;
    if (t < NAG) {
        v = bias3[0];
#pragma unroll
        for (int k = 0; k < KK; k++) v += alphaS[t*KK + k] * xl3S[nbr[t*KK + k]];
    }
    if (t < 64) {
#pragma unroll
        for (int o = 32; o > 0; o >>= 1) v += __shfl_xor(v, o);
        if (t == 0) resS = v;
    }
    __syncthreads();
    if (t < NAG) out[g*NAG + t] = resS;
}

extern "C" void kernel_launch(void* const* d_in, const int* in_sizes, int n_in,
                              void* d_out, int out_size, void* d_ws, size_t ws_size,
                              hipStream_t stream)
{
    const float* obst = (const float*)d_in[0];
    const float* apos = (const float*)d_in[1];
    const float* gpos = (const float*)d_in[2];
    const float* avel = (const float*)d_in[3];
    const int B = in_sizes[1] / (NAG * 2);

    e3_kernel<<<B, TPB, 0, stream>>>(
        obst, apos, gpos, avel,
        (const float*)d_in[4],  (const float*)d_in[5],  (const float*)d_in[6],
        (const float*)d_in[7],  (const float*)d_in[8],  (const float*)d_in[9],
        (const float*)d_in[10],
        (const float*)d_in[11], (const float*)d_in[12], (const float*)d_in[13],
        (const float*)d_in[14], (const float*)d_in[15], (const float*)d_in[16],
        (const float*)d_in[17],
        (const float*)d_in[18], (const float*)d_in[19], (const float*)d_in[20],
        (const float*)d_in[21], (const float*)d_in[22], (const float*)d_in[23],
        (const float*)d_in[24],
        (float*)d_out);
}

// Round 17
// 116.565 us; speedup vs baseline: 1.7114x; 1.1096x over previous
//
#include <hip/hip_runtime.h>
#include <math.h>

typedef float floatx4 __attribute__((ext_vector_type(4)));
typedef short bf16x8  __attribute__((ext_vector_type(8)));   // 8 bf16 = 4 VGPRs (guide §3)

#define NAG   32
#define NOBS  16
#define NN    80
#define KK    5
#define EKNN  400   // NN*KK
#define ED    416   // EKNN + NOBS = 26 * 16 exactly
#define HID   128
#define TPB   1024

// bf16-row swizzle, uint2-chunk units (row bits into bank bits).
__device__ __forceinline__ int bsw(int n, int c) { return c ^ ((n & 7) << 1); }

__device__ __forceinline__ float bfhi_f(unsigned u) {
    union { unsigned u; float f; } v; v.u = u & 0xffff0000u; return v.f;
}
__device__ __forceinline__ float bflo_f(unsigned u) {
    union { unsigned u; float f; } v; v.u = u << 16; return v.f;
}
__device__ __forceinline__ unsigned f_bf_rne(float f) {   // bf16 in low 16 bits
    union { float f; unsigned u; } v; v.f = f;
    return (v.u + 0x7fffu + ((v.u >> 16) & 1u)) >> 16;
}
__device__ __forceinline__ uint2 pack_bf4v(floatx4 a) {
    uint2 r;
    r.x = f_bf_rne(a[0]) | (f_bf_rne(a[1]) << 16);
    r.y = f_bf_rne(a[2]) | (f_bf_rne(a[3]) << 16);
    return r;
}
__device__ __forceinline__ floatx4 unpack_bf4v(uint2 p) {
    floatx4 r;
    r[0] = bflo_f(p.x); r[1] = bfhi_f(p.x);
    r[2] = bflo_f(p.y); r[3] = bfhi_f(p.y);
    return r;
}

// ---- layer-1 node-linear (F_IN=5, tiny W read direct from global) ----
__device__ __forceinline__ void nl_pass5(const float* xf,
    const float* __restrict__ W, const float* __restrict__ bv,
    uint2* dstB, int t)
{
    const int q  = t & 31;
    const int ng = t >> 5;
    const int n0 = ng, n1 = ng + 32, n2 = 64 + (ng & 15);
    floatx4 a0 = {0.f,0.f,0.f,0.f}, a1 = a0, a2 = a0;
#pragma unroll
    for (int fi = 0; fi < 5; ++fi) {
        floatx4 wv = *(const floatx4*)(W + fi*HID + q*4);
        a0 += xf[n0*5 + fi] * wv;
        a1 += xf[n1*5 + fi] * wv;
        a2 += xf[n2*5 + fi] * wv;
    }
    floatx4 b4 = *(const floatx4*)(bv + q*4);
    a0 += b4; a1 += b4; a2 += b4;
    dstB[n0*32 + bsw(n0, q)] = pack_bf4v(a0);
    dstB[n1*32 + bsw(n1, q)] = pack_bf4v(a1);
    if (ng < 16) dstB[n2*32 + bsw(n2, q)] = pack_bf4v(a2);
}

// ---- MFMA D-tile store: D(row,col) = acc[rr] + bias[col] -> bf16 @ bsw layout ----
__device__ __forceinline__ void store_tile(floatx4 ac, int mtbase, int l, int col,
                                           float bval, char* dbase)
{
#pragma unroll
    for (int rr = 0; rr < 4; rr++) {
        int row = mtbase + ((l >> 4) << 2) + rr;
        int ch  = (col >> 2) ^ ((row & 7) << 1);
        *(unsigned short*)(dbase + row*256 + ch*8 + (col & 3)*2) =
            (unsigned short)f_bf_rne(ac[rr] + bval);
    }
}

// ---- edge logits via MFMA: P^T tile = (We^T c-tile) x (ea^T edge-tile) ----
// mfma_f32_16x16x32_bf16, K padded 5->32 with zeros (only lanes<16 carry data).
// D: lane l -> edge = mt*16 + (l&15)  (FIXED per lane), c = ct*16 + 4*(l>>4)+rr
// -> per ct the lane's 4 c's are contiguous: 1 uint2 xl + 1 uint2 xr + 1 f4 att.
// Reduction over the 4 lane-groups: 2 shfl_xor (16, 32).
__device__ __forceinline__ void edge_mfma(const uint2* xlB, const uint2* xrB,
    const uint4* WeBfT, const uint4* eaB, const unsigned short* sdS,
    const int* gmask, const float* attS, float* logitS, int t)
{
    const int w = t >> 6, l = t & 63;
    const int g = l >> 4, e16 = l & 15;
    const bf16x8 zf = {0,0,0,0,0,0,0,0};

#pragma unroll 1
    for (int rep = 0; rep < 2; rep++) {
        const int mt = w + rep*16;       // wave-uniform
        if (mt >= 26) break;
        const int e = mt*16 + e16;
        const unsigned sdv = sdS[e];
        const int src = sdv & 0xff, dst = sdv >> 8;
        const int sb = src*32, db = dst*32;
        const int sx = (src & 7) << 1, dx = (dst & 7) << 1;
        bf16x8 bfrag = (l < 16) ? ((const bf16x8*)eaB)[e] : zf;
        float partial = 0.f;

#pragma unroll 1
        for (int ct = 0; ct < 8; ct++) {
            bf16x8 afrag = (l < 16) ? ((const bf16x8*)WeBfT)[ct*16 + e16] : zf;
            floatx4 D = {0.f,0.f,0.f,0.f};
            D = __builtin_amdgcn_mfma_f32_16x16x32_bf16(afrag, bfrag, D, 0, 0, 0);
            floatx4 attv = ((const floatx4*)attS)[ct*4 + g];
            floatx4 xlv = unpack_bf4v(xlB[sb + ((4*ct + g) ^ sx)]);
            floatx4 xrv = unpack_bf4v(xrB[db + ((4*ct + g) ^ dx)]);
#pragma unroll
            for (int rr = 0; rr < 4; rr++) {
                float s = D[rr] + xlv[rr] + xrv[rr];
                float m = fmaxf(s, 0.2f*s);          // leaky_relu(s, 0.2)
                partial = fmaf(m, attv[rr], partial);
            }
        }
        partial += __shfl_xor(partial, 16);
        partial += __shfl_xor(partial, 32);
        if (l < 16) {
            bool act = (e < EKNN) || (gmask[e - EKNN] != 0);
            if (act) logitS[e] = partial;
        }
    }
}

// ---- per-dst softmax over incoming edges (5 knn + optional goal edge) ----
__device__ __forceinline__ void seg_softmax(const float* logitS, const int* gmask,
                                            float* alphaS, int t)
{
    if (t < NN) {
        const int n = t;
        float l[KK];
#pragma unroll
        for (int k = 0; k < KK; k++) l[k] = logitS[n*KK + k];
        float m = l[0];
#pragma unroll
        for (int k = 1; k < KK; k++) m = fmaxf(m, l[k]);
        int ge = -1; float lg = 0.f;
        if (n >= NAG && n < NAG + NOBS && gmask[n - NAG]) {
            ge = EKNN + (n - NAG);
            lg = logitS[ge];
            m = fmaxf(m, lg);
        }
        float s = 0.f, av[KK];
#pragma unroll
        for (int k = 0; k < KK; k++) { av[k] = expf(l[k] - m); s += av[k]; }
        float ag = 0.f;
        if (ge >= 0) { ag = expf(lg - m); s += ag; }
        float inv = 1.f / s;
#pragma unroll
        for (int k = 0; k < KK; k++) alphaS[n*KK + k] = av[k]*inv;
        if (ge >= 0) alphaS[ge] = ag*inv;
    }
}

// ---- h[n][f] = relu(bias[f] + sum_e alpha_e * xl[src_e][f]) -> bf16 hxrS ----
__device__ __forceinline__ void aggregate(const uint2* xlB, const float* alphaS,
                                          const int* nbr, const int* gmask,
                                          const float* __restrict__ bias,
                                          uint2* hxr, int t)
{
    for (int idx = t; idx < NN*32; idx += TPB) {
        int n = idx >> 5;
        int c = idx & 31;
        floatx4 acc = *(const floatx4*)(bias + 4*c);
#pragma unroll
        for (int k = 0; k < KK; k++) {
            float a = alphaS[n*KK + k];
            int s = nbr[n*KK + k];
            acc += a * unpack_bf4v(xlB[s*32 + bsw(s, c)]);
        }
        if (n >= NAG && n < NAG + NOBS && gmask[n - NAG]) {
            float a = alphaS[EKNN + (n - NAG)];
            int s = n - NAG;
            acc += a * unpack_bf4v(xlB[s*32 + bsw(s, c)]);
        }
#pragma unroll
        for (int c2 = 0; c2 < 4; c2++) acc[c2] = fmaxf(acc[c2], 0.f);
        hxr[n*32 + bsw(n, c)] = pack_bf4v(acc);
    }
}

// launch_bounds(1024, 8): VGPR budget 32 — the only config that co-schedules
// 2 blocks/CU (empirical: vgpr=32 -> 80-89% occupancy; 48/56/64 -> 47%).
// LDS ~75.8KB: 2x <= 160KB.
__global__ __launch_bounds__(TPB, 8) void e3_kernel(
    const float* __restrict__ obst, const float* __restrict__ apos,
    const float* __restrict__ gpos, const float* __restrict__ avel,
    const float* __restrict__ Wl1, const float* __restrict__ bl1,
    const float* __restrict__ Wr1, const float* __restrict__ br1,
    const float* __restrict__ We1, const float* __restrict__ att1, const float* __restrict__ bias1,
    const float* __restrict__ Wl2, const float* __restrict__ bl2,
    const float* __restrict__ Wr2, const float* __restrict__ br2,
    const float* __restrict__ We2, const float* __restrict__ att2, const float* __restrict__ bias2,
    const float* __restrict__ Wl3, const float* __restrict__ bl3,
    const float* __restrict__ Wr3, const float* __restrict__ br3,
    const float* __restrict__ We3, const float* __restrict__ att3, const float* __restrict__ bias3,
    float* __restrict__ out)
{
    __shared__ float pos0[NN], pos1[NN], vel0[NN], vel1[NN], rad[NN];
    __shared__ float xfeat[NN*5];
    __shared__ int   nbr[NN*KK];
    __shared__ int   gmask[NOBS];
    __shared__ float eaS[ED*5];
    __shared__ float logitS[ED];
    __shared__ float alphaS[ED];
    __shared__ unsigned short sdS[ED];       // src | dst<<8 per edge
    __shared__ uint2 hxrS[NN*32];            // bf16 h AND bf16 xr (time-shared)
    __shared__ uint2 xlB[NN*32];             // bf16 xl
    __shared__ uint4 BfS[2*8*64];            // 16KB union: GEMM B-frags | {WeBfT[128], eaB[416]}
    __shared__ float attS[HID];
    __shared__ float xl3S[NN], xr3S[NN];
    __shared__ float resS;

    uint4* WeBfT = BfS;          // [128]: We^T A-frags (c row, k 0..7, 0-pad k>=5)
    uint4* eaB   = BfS + 128;    // [416]: ea B-frags  (edge col, k 0..7, 0-pad)

    const int g = blockIdx.x;
    const int t = threadIdx.x;

    // ---------- phase A: load graph ----------
    if (t < NN) {
        int n = t;
        float px, py, vx = 0.f, vy = 0.f, r;
        if (n < NAG) {
            px = apos[(g*NAG + n)*2 + 0]; py = apos[(g*NAG + n)*2 + 1];
            vx = avel[(g*NAG + n)*2 + 0]; vy = avel[(g*NAG + n)*2 + 1];
            r = 0.05f;
        } else if (n < 2*NAG) {
            int m = n - NAG;
            px = gpos[(g*NAG + m)*2 + 0]; py = gpos[(g*NAG + m)*2 + 1];
            r = 0.f;
        } else {
            int m = n - 2*NAG;
            px = obst[(g*NOBS + m)*2 + 0]; py = obst[(g*NOBS + m)*2 + 1];
            r = 0.1f;
        }
        pos0[n] = px; pos1[n] = py; vel0[n] = vx; vel1[n] = vy; rad[n] = r;
        xfeat[n*5 + 0] = (n < NAG) ? 1.f : 0.f;
        xfeat[n*5 + 1] = (n >= NAG && n < 2*NAG) ? 1.f : 0.f;
        xfeat[n*5 + 2] = (n >= 2*NAG) ? 1.f : 0.f;
        xfeat[n*5 + 3] = (n < NAG) ? sqrtf(__fadd_rn(__fmul_rn(vx,vx), __fmul_rn(vy,vy))) : 0.f;
        xfeat[n*5 + 4] = r;
    }
    __syncthreads();

    // ---------- phase B: kNN top-5 (ascending d2, stable on ties == top_k) ----------
    if (t < NN) {
        const int i = t;
        float bd[KK]; int bi[KK];
#pragma unroll
        for (int k = 0; k < KK; k++) { bd[k] = 3.4e38f; bi[k] = -1; }
        const float pix = pos0[i], piy = pos1[i];
        for (int j = 0; j < NN; j++) {
            float dx = __fsub_rn(pix, pos0[j]);
            float dy = __fsub_rn(piy, pos1[j]);
            float d2 = __fadd_rn(__fmul_rn(dx,dx), __fmul_rn(dy,dy));
            if (d2 < bd[KK-1]) {
                int p = KK - 1;
                while (p > 0 && d2 < bd[p-1]) { bd[p] = bd[p-1]; bi[p] = bi[p-1]; p--; }
                bd[p] = d2; bi[p] = j;
            }
        }
#pragma unroll
        for (int k = 0; k < KK; k++) nbr[i*KK + k] = bi[k];
    }
    __syncthreads();

    // goal-edge dedup mask
    if (t < NOBS) {
        int j = t, dup = 0;
#pragma unroll
        for (int k = 0; k < KK; k++) dup |= (nbr[(NAG + j)*KK + k] == j);
        gmask[j] = !dup;
    }
    __syncthreads();

    // ---------- phase C: edge attributes (+ sd table + bf16 ea B-frags) ----------
    for (int e = t; e < ED; e += TPB) {
        int src, dst;
        if (e < EKNN) { dst = e / KK; src = nbr[e]; }
        else          { src = e - EKNN; dst = src + NAG; }
        float pdx = pos0[src] - pos0[dst];
        float pdy = pos1[src] - pos1[dst];
        float dist = sqrtf(pdx*pdx + pdy*pdy);
        float inv = 1.f / fmaxf(dist, 1e-6f);
        float pnx = pdx * inv, pny = pdy * inv;
        float rvx = vel0[src] - vel0[dst];
        float rvy = vel1[src] - vel1[dst];
        float e0 = (src < NAG && dst == src + NAG) ? 1.f : 0.f;
        float e1 = dist;
        float e2 = dist - (rad[src] + rad[dst]);
        float e3 = rvx*pnx + rvy*pny;
        float e4 = rvx*pny - rvy*pnx;
        eaS[e*5 + 0] = e0; eaS[e*5 + 1] = e1; eaS[e*5 + 2] = e2;
        eaS[e*5 + 3] = e3; eaS[e*5 + 4] = e4;
        sdS[e] = (unsigned short)(src | (dst << 8));
        uint4 pk;
        pk.x = f_bf_rne(e0) | (f_bf_rne(e1) << 16);
        pk.y = f_bf_rne(e2) | (f_bf_rne(e3) << 16);
        pk.z = f_bf_rne(e4);
        pk.w = 0u;
        eaB[e] = pk;
    }

    // ================= layer 1 (F_IN=5) =================
    // stage We1^T A-frags + att1 (independent of the nl_pass5 writes)
    if (t < HID) {
        uint4 pw;
        pw.x = f_bf_rne(We1[0*HID + t]) | (f_bf_rne(We1[1*HID + t]) << 16);
        pw.y = f_bf_rne(We1[2*HID + t]) | (f_bf_rne(We1[3*HID + t]) << 16);
        pw.z = f_bf_rne(We1[4*HID + t]);
        pw.w = 0u;
        WeBfT[t] = pw;
        attS[t] = att1[t];
    }
    __syncthreads();   // covers phase C + staging (xfeat stable since phase A)

    nl_pass5(xfeat, Wl1, bl1, xlB,  t);
    nl_pass5(xfeat, Wr1, br1, hxrS, t);
    __syncthreads();
    edge_mfma(xlB, hxrS, WeBfT, eaB, sdS, gmask, attS, logitS, t);
    __syncthreads();
    seg_softmax(logitS, gmask, alphaS, t);
    __syncthreads();
    aggregate(xlB, alphaS, nbr, gmask, bias1, hxrS, t);
    __syncthreads();

    // ================= layer 2: dual GEMM on the MATRIX pipe =================
    // (unchanged from r16 — layouts HW-verified). Clobbers BfS; restaged after.
    if (t < HID) attS[t] = att2[t];
    {
        const int w   = t >> 6;          // wave 0..15
        const int l   = t & 63;
        const int mat = w >> 3;
        const int nt  = w & 7;
        const int ar  = l & 15;
        const int kg2 = (l >> 4) << 1;
        const int arx = (ar & 7) << 1;

        const int sm = t >> 9;           // staging: matrix
        const int s  = t & 511;
        const int sn = s & 127;          // column
        const int g8 = s >> 7;           // k-octet 0..3
        const float* __restrict__ Wst = sm ? Wr2 : Wl2;
        const int swidx = sm*512 + (sn >> 4)*64 + ((sn & 15) | (g8 << 4));

        floatx4 acc0 = {0.f,0.f,0.f,0.f}, acc1 = acc0, acc2 = acc0,
                acc3 = acc0, acc4 = acc0;

#pragma unroll 1
        for (int kb = 0; kb < 4; ++kb) {
            const float* wp = Wst + (kb*32 + g8*8)*HID + sn;
            uint4 pk;
            pk.x = f_bf_rne(wp[0])     | (f_bf_rne(wp[HID])   << 16);
            pk.y = f_bf_rne(wp[2*HID]) | (f_bf_rne(wp[3*HID]) << 16);
            pk.z = f_bf_rne(wp[4*HID]) | (f_bf_rne(wp[5*HID]) << 16);
            pk.w = f_bf_rne(wp[6*HID]) | (f_bf_rne(wp[7*HID]) << 16);
            BfS[swidx] = pk;
            __syncthreads();

            bf16x8 bfrag = ((const bf16x8*)BfS)[mat*512 + nt*64 + l];
            const char* hbase = (const char*)hxrS;
            const int cA = ((kb*8 + kg2) ^ arx) * 8;
#define MT_MFMA(AC, MT) { \
            bf16x8 af = *(const bf16x8*)(hbase + (MT*4096) + ar*256 + cA); \
            AC = __builtin_amdgcn_mfma_f32_16x16x32_bf16(af, bfrag, AC, 0, 0, 0); }
            MT_MFMA(acc0, 0)
            MT_MFMA(acc1, 1)
            MT_MFMA(acc2, 2)
            MT_MFMA(acc3, 3)
            MT_MFMA(acc4, 4)
#undef MT_MFMA
            __syncthreads();   // chunk reuse fence; final iter = all h reads done
        }

        const float* __restrict__ bv = mat ? br2 : bl2;
        char* dbase = (char*)(mat ? hxrS : xlB);
        const int col = nt*16 + ar;
        const float bval = bv[col];
        store_tile(acc0,  0, l, col, bval, dbase);
        store_tile(acc1, 16, l, col, bval, dbase);
        store_tile(acc2, 32, l, col, bval, dbase);
        store_tile(acc3, 48, l, col, bval, dbase);
        store_tile(acc4, 64, l, col, bval, dbase);
    }

    // restage We2^T + eaB (BfS was clobbered; eaS is still live)
    if (t < HID) {
        uint4 pw;
        pw.x = f_bf_rne(We2[0*HID + t]) | (f_bf_rne(We2[1*HID + t]) << 16);
        pw.y = f_bf_rne(We2[2*HID + t]) | (f_bf_rne(We2[3*HID + t]) << 16);
        pw.z = f_bf_rne(We2[4*HID + t]);
        pw.w = 0u;
        WeBfT[t] = pw;
    } else if (t < HID + ED) {
        int e = t - HID;
        uint4 pk;
        pk.x = f_bf_rne(eaS[e*5+0]) | (f_bf_rne(eaS[e*5+1]) << 16);
        pk.y = f_bf_rne(eaS[e*5+2]) | (f_bf_rne(eaS[e*5+3]) << 16);
        pk.z = f_bf_rne(eaS[e*5+4]);
        pk.w = 0u;
        eaB[e] = pk;
    }
    __syncthreads();

    edge_mfma(xlB, hxrS, WeBfT, eaB, sdS, gmask, attS, logitS, t);
    __syncthreads();
    seg_softmax(logitS, gmask, alphaS, t);
    __syncthreads();
    aggregate(xlB, alphaS, nbr, gmask, bias2, hxrS, t);
    __syncthreads();

    // ================= layer 3 (F_out = 1) =================
    {
        const int q   = t & 31;
        const int grp = t >> 5;
        floatx4 wl4 = *(const floatx4*)(Wl3 + q*4);
        floatx4 wr4 = *(const floatx4*)(Wr3 + q*4);
#pragma unroll
        for (int rep = 0; rep < 3; rep++) {
            int n = grp + rep*32;
            if (n < NN) {
                floatx4 hv = unpack_bf4v(hxrS[n*32 + bsw(n, q)]);
                float al = hv[0]*wl4[0] + hv[1]*wl4[1] + hv[2]*wl4[2] + hv[3]*wl4[3];
                float ar3 = hv[0]*wr4[0] + hv[1]*wr4[1] + hv[2]*wr4[2] + hv[3]*wr4[3];
                al += __shfl_xor(al, 16); ar3 += __shfl_xor(ar3, 16);
                al += __shfl_xor(al, 8);  ar3 += __shfl_xor(ar3, 8);
                al += __shfl_xor(al, 4);  ar3 += __shfl_xor(ar3, 4);
                al += __shfl_xor(al, 2);  ar3 += __shfl_xor(ar3, 2);
                al += __shfl_xor(al, 1);  ar3 += __shfl_xor(ar3, 1);
                if (q == 0) {
                    xl3S[n] = al + bl3[0];
                    xr3S[n] = ar3 + br3[0];
                }
            }
        }
    }
    __syncthreads();

    {
        float w0 = We3[0], w1 = We3[1], w2 = We3[2], w3 = We3[3], w4 = We3[4];
        float a0 = att3[0];
        for (int e = t; e < ED; e += TPB) {
            int src, dst;
            if (e < EKNN) { dst = e / KK; src = nbr[e]; }
            else { src = e - EKNN; dst = src + NAG; if (!gmask[src]) continue; }
            float s = xl3S[src] + xr3S[dst]
                    + eaS[e*5+0]*w0 + eaS[e*5+1]*w1 + eaS[e*5+2]*w2
                    + eaS[e*5+3]*w3 + eaS[e*5+4]*w4;
            s = fmaxf(s, 0.2f*s);
            logitS[e] = s * a0;
        }
    }
    __syncthreads();

    seg_softmax(logitS, gmask, alphaS, t);
    __syncthreads();

    // final: sum over agent nodes of (bias3 + sum_e alpha*xl3[src]); broadcast to 32 outputs
    float v = 0.f;
    if (t < NAG) {
        v = bias3[0];
#pragma unroll
        for (int k = 0; k < KK; k++) v += alphaS[t*KK + k] * xl3S[nbr[t*KK + k]];
    }
    if (t < 64) {
#pragma unroll
        for (int o = 32; o > 0; o >>= 1) v += __shfl_xor(v, o);
        if (t == 0) resS = v;
    }
    __syncthreads();
    if (t < NAG) out[g*NAG + t] = resS;
}

extern "C" void kernel_launch(void* const* d_in, const int* in_sizes, int n_in,
                              void* d_out, int out_size, void* d_ws, size_t ws_size,
                              hipStream_t stream)
{
    const float* obst = (const float*)d_in[0];
    const float* apos = (const float*)d_in[1];
    const float* gpos = (const float*)d_in[2];
    const float* avel = (const float*)d_in[3];
    const int B = in_sizes[1] / (NAG * 2);

    e3_kernel<<<B, TPB, 0, stream>>>(
        obst, apos, gpos, avel,
        (const float*)d_in[4],  (const float*)d_in[5],  (const float*)d_in[6],
        (const float*)d_in[7],  (const float*)d_in[8],  (const float*)d_in[9],
        (const float*)d_in[10],
        (const float*)d_in[11], (const float*)d_in[12], (const float*)d_in[13],
        (const float*)d_in[14], (const float*)d_in[15], (const float*)d_in[16],
        (const float*)d_in[17],
        (const float*)d_in[18], (const float*)d_in[19], (const float*)d_in[20],
        (const float*)d_in[21], (const float*)d_in[22], (const float*)d_in[23],
        (const float*)d_in[24],
        (float*)d_out);
}